// Round 1
// baseline (560.891 us; speedup 1.0000x reference)
//
#include <hip/hip_runtime.h>
#include <stdint.h>

typedef unsigned short u16;
typedef unsigned int u32;
typedef __bf16 bf16x8 __attribute__((ext_vector_type(8)));
typedef float f32x4 __attribute__((ext_vector_type(4)));
typedef unsigned short u16x8 __attribute__((ext_vector_type(8)));

#define D_MODEL 1024
#define SEQ 2048
#define NH 16
#define DK 64
#define NROWS 4096  // B*S

static __device__ __forceinline__ u16 f2bf(float f) {
  u32 u = __float_as_uint(f);
  u = (u + 0x7FFFu + ((u >> 16) & 1u)) >> 16;
  return (u16)u;
}
static __device__ __forceinline__ float bf2f(u16 h) {
  return __uint_as_float(((u32)h) << 16);
}
static __device__ __forceinline__ f32x4 mfma16(bf16x8 a, bf16x8 b, f32x4 c) {
  return __builtin_amdgcn_mfma_f32_16x16x32_bf16(a, b, c, 0, 0, 0);
}

// ---------------- fp32 -> bf16 cast of x and the 4 weight matrices ----------------
__global__ __launch_bounds__(256) void k_cast(
    const float* __restrict__ x, const float* __restrict__ wq,
    const float* __restrict__ wk, const float* __restrict__ wv,
    const float* __restrict__ wo, u16* __restrict__ xb, u16* __restrict__ wqb,
    u16* __restrict__ wkb, u16* __restrict__ wvb, u16* __restrict__ wob) {
  size_t e = ((size_t)blockIdx.x * 256 + threadIdx.x) * 8;
  const float* s;
  u16* d;
  size_t off;
  if (e < (size_t)NROWS * D_MODEL) {
    s = x; d = xb; off = e;
  } else {
    size_t r = e - (size_t)NROWS * D_MODEL;
    unsigned wi = (unsigned)(r >> 20);
    off = r & 1048575u;
    s = wi == 0 ? wq : wi == 1 ? wk : wi == 2 ? wv : wo;
    d = wi == 0 ? wqb : wi == 1 ? wkb : wi == 2 ? wvb : wob;
  }
  float4 a = *(const float4*)(s + off);
  float4 b = *(const float4*)(s + off + 4);
  u16x8 o;
  o[0] = f2bf(a.x); o[1] = f2bf(a.y); o[2] = f2bf(a.z); o[3] = f2bf(a.w);
  o[4] = f2bf(b.x); o[5] = f2bf(b.y); o[6] = f2bf(b.z); o[7] = f2bf(b.w);
  *(u16x8*)(d + off) = o;
}

// ---------------- RoPE tables (fp64 on device -> fp32 tables) ----------------
__global__ __launch_bounds__(256) void k_tab(float* __restrict__ ct, float* __restrict__ st) {
  int i = blockIdx.x * 256 + threadIdx.x;  // 2048*32
  int s = i >> 5, p = i & 31;
  double ang = (double)s * pow(10000.0, -(double)p / 32.0);
  ct[i] = (float)cos(ang);
  st[i] = (float)sin(ang);
}

// ---------------- bf16 B^T GEMM: C[M,N] = A[M,K] * B'[N,K]^T, K=1024 ----------------
// 128x128 tile, 4 waves of 64x64, 16x16x32 MFMA, register-staged LDS w/ prefetch.
template <bool MULTI, bool OUTF32>
__global__ __launch_bounds__(256) void k_gemm(
    const u16* __restrict__ A, const u16* __restrict__ B0,
    const u16* __restrict__ B1, const u16* __restrict__ B2,
    u16* __restrict__ Cb, float* __restrict__ Cf, int ldc) {
  constexpr int K = 1024;
  const int mb = blockIdx.x, nb = blockIdx.y;
  const int tid = threadIdx.x;
  const int lane = tid & 63, w = tid >> 6;
  const int lq = lane & 15, lg = lane >> 4;
  const int wm = w >> 1, wn = w & 1;
  __shared__ __align__(16) u16 As[128 * 32];
  __shared__ __align__(16) u16 Bs[128 * 32];

  const u16* Bp;
  if (MULTI) {
    int sel = nb >> 3;
    Bp = sel == 0 ? B0 : (sel == 1 ? B1 : B2);
  } else {
    Bp = B0;
  }
  int nloc = MULTI ? (nb & 7) * 128 : nb * 128;
  const char* Ab = (const char*)A + (size_t)mb * 128 * 2048;
  const char* Bb = (const char*)Bp + (size_t)nloc * 2048;

  const int srow = tid >> 2;        // staging row (tid*16 bytes -> row o>>6)
  const int scb = (tid & 3) * 16;   // staging col bytes

  f32x4 zero4 = {0.f, 0.f, 0.f, 0.f};
  f32x4 acc[4][4];
#pragma unroll
  for (int i = 0; i < 4; ++i)
#pragma unroll
    for (int j = 0; j < 4; ++j) acc[i][j] = zero4;

  uint4 areg[2], breg[2];
#pragma unroll
  for (int c = 0; c < 2; ++c) {
    size_t go = (size_t)(srow + c * 64) * 2048 + scb;
    areg[c] = *(const uint4*)(Ab + go);
    breg[c] = *(const uint4*)(Bb + go);
  }

  for (int k0 = 0; k0 < K; k0 += 32) {
#pragma unroll
    for (int c = 0; c < 2; ++c) {
      int o = (srow + c * 64) * 64 + scb;
      *(uint4*)((char*)As + o) = areg[c];
      *(uint4*)((char*)Bs + o) = breg[c];
    }
    __syncthreads();
    uint4 an[2], bn[2];
    if (k0 + 32 < K) {
#pragma unroll
      for (int c = 0; c < 2; ++c) {
        size_t go = (size_t)(srow + c * 64) * 2048 + (k0 + 32) * 2 + scb;
        an[c] = *(const uint4*)(Ab + go);
        bn[c] = *(const uint4*)(Bb + go);
      }
    } else {
      an[0] = areg[0]; an[1] = areg[1]; bn[0] = breg[0]; bn[1] = breg[1];
    }
    bf16x8 af[4], bfr[4];
#pragma unroll
    for (int i = 0; i < 4; ++i) {
      af[i] = *(const bf16x8*)((const char*)As + (wm * 64 + i * 16 + lq) * 64 + lg * 16);
      bfr[i] = *(const bf16x8*)((const char*)Bs + (wn * 64 + i * 16 + lq) * 64 + lg * 16);
    }
#pragma unroll
    for (int i = 0; i < 4; ++i)
#pragma unroll
      for (int j = 0; j < 4; ++j) acc[i][j] = mfma16(af[i], bfr[j], acc[i][j]);
    __syncthreads();
    areg[0] = an[0]; areg[1] = an[1]; breg[0] = bn[0]; breg[1] = bn[1];
  }

#pragma unroll
  for (int i = 0; i < 4; ++i) {
#pragma unroll
    for (int r = 0; r < 4; ++r) {
      size_t rowg = (size_t)(mb * 128 + wm * 64 + i * 16 + lg * 4 + r);
#pragma unroll
      for (int j = 0; j < 4; ++j) {
        int colg = nb * 128 + wn * 64 + j * 16 + lq;
        if (OUTF32)
          Cf[rowg * ldc + colg] = acc[i][j][r];
        else
          Cb[rowg * ldc + colg] = f2bf(acc[i][j][r]);
      }
    }
  }
}

// ---------------- RoPE apply + reshape to head-major [BH][S][64] ----------------
__global__ __launch_bounds__(256) void k_rope(const u16* __restrict__ qkv,
                                              const float* __restrict__ ct,
                                              const float* __restrict__ st,
                                              u16* __restrict__ qh, u16* __restrict__ kh) {
  int gi = blockIdx.x * 256 + threadIdx.x;  // 524288
  int row = gi >> 7;
  int col = (gi & 127) << 3;
  int h = col >> 6, d0 = col & 63;
  int b = row >> 11, s = row & 2047;
  const int srcoff = blockIdx.y ? 1024 : 0;
  u16x8 v = *(const u16x8*)(qkv + (size_t)row * 3072 + srcoff + col);
  const float* cp = ct + s * 32 + (d0 >> 1);
  const float* sp = st + s * 32 + (d0 >> 1);
  u16x8 o;
#pragma unroll
  for (int i = 0; i < 4; ++i) {
    float ev = bf2f(v[2 * i]), od = bf2f(v[2 * i + 1]);
    float c = cp[i], sn = sp[i];
    o[2 * i] = f2bf(ev * c - od * sn);
    o[2 * i + 1] = f2bf(ev * sn + od * c);
  }
  u16* dst = blockIdx.y ? kh : qh;
  *(u16x8*)(dst + (((size_t)(b * 16 + h) * SEQ + s) << 6) + d0) = o;
}

// ---------------- V transpose: qkv V cols -> Vt [BH][64][S] ----------------
__global__ __launch_bounds__(256) void k_vtrans(const u16* __restrict__ qkv,
                                                u16* __restrict__ vt) {
  __shared__ __align__(16) u16 t[64][72];
  int sb = blockIdx.x, bh = blockIdx.y;
  int b = bh >> 4, h = bh & 15;
  int tid = threadIdx.x;
#pragma unroll
  for (int c = 0; c < 2; ++c) {
    int o = tid * 8 + c * 2048;
    int r = o >> 6, d = o & 63;
    u16x8 v = *(const u16x8*)(qkv + (size_t)(b * SEQ + sb * 64 + r) * 3072 + 2048 + h * 64 + d);
    *(u16x8*)&t[r][d] = v;
  }
  __syncthreads();
#pragma unroll
  for (int c = 0; c < 2; ++c) {
    int o = tid * 8 + c * 2048;
    int d = o >> 6, si = o & 63;
    u16x8 v;
#pragma unroll
    for (int j = 0; j < 8; ++j) v[j] = t[si + j][d];
    *(u16x8*)(vt + ((size_t)bh * 64 + d) * SEQ + sb * 64 + si) = v;
  }
}

// ---------------- causal flash attention ----------------
// grid (32 qblocks, 32 bh); 4 waves x 16 q-rows; KV block 64; swapped QK^T.
__global__ __launch_bounds__(256) void k_attn(const u16* __restrict__ qh,
                                              const u16* __restrict__ kh,
                                              const u16* __restrict__ vt,
                                              u16* __restrict__ ao) {
  const int qb = (int)(gridDim.x - 1u - blockIdx.x);  // heavy blocks first
  const int bh = blockIdx.y;
  const int tid = threadIdx.x;
  const int w = tid >> 6;
  const int lane = tid & 63;
  const int lq = lane & 15;
  const int lg = lane >> 4;

  __shared__ __align__(16) u16 Kl[64 * 64];
  __shared__ __align__(16) u16 Vl[64 * 64];
  __shared__ __align__(16) u16 Pl[4][16 * 64];

  const int q0 = qb * 64;
  const int qrow = q0 + w * 16 + lq;

  const u16* qptr = qh + ((size_t)bh * SEQ + qrow) * DK + lg * 8;
  bf16x8 qf0 = *(const bf16x8*)qptr;
  bf16x8 qf1 = *(const bf16x8*)(qptr + 32);

  f32x4 zero4 = {0.f, 0.f, 0.f, 0.f};
  f32x4 accO[4];
  accO[0] = zero4; accO[1] = zero4; accO[2] = zero4; accO[3] = zero4;
  float m_run = -1e30f, l_run = 0.f;

  const int nkv = qb + 1;
  const int srow = tid >> 3;       // 0..31
  const int scb = (tid & 7) * 16;  // byte col in 128B row

  uint4 kreg[2], vreg[2];
#pragma unroll
  for (int c = 0; c < 2; ++c) {
    int r = srow + c * 32;
    kreg[c] = *(const uint4*)((const char*)(kh + ((size_t)bh * SEQ + r) * DK) + scb);
    vreg[c] = *(const uint4*)((const char*)(vt + ((size_t)bh * DK + r) * SEQ) + scb);
  }

  for (int t = 0; t < nkv; ++t) {
#pragma unroll
    for (int c = 0; c < 2; ++c) {
      int r = srow + c * 32;
      int ad = (r * 128 + scb) ^ ((r & 7) << 4);
      *(uint4*)((char*)Kl + ad) = kreg[c];
      *(uint4*)((char*)Vl + ad) = vreg[c];
    }
    __syncthreads();

    uint4 k2[2], v2[2];
    if (t + 1 < nkv) {
      int k0n = (t + 1) * 64;
#pragma unroll
      for (int c = 0; c < 2; ++c) {
        int r = srow + c * 32;
        k2[c] = *(const uint4*)((const char*)(kh + ((size_t)bh * SEQ + k0n + r) * DK) + scb);
        v2[c] = *(const uint4*)((const char*)(vt + ((size_t)bh * DK + r) * SEQ + k0n) + scb);
      }
    } else {
      k2[0] = kreg[0]; k2[1] = kreg[1]; v2[0] = vreg[0]; v2[1] = vreg[1];
    }

    // QK^T, swapped: D[key][q]
    f32x4 sa[4];
    sa[0] = zero4; sa[1] = zero4; sa[2] = zero4; sa[3] = zero4;
#pragma unroll
    for (int kt = 0; kt < 4; ++kt) {
      int krow = kt * 16 + lq;
      int base = krow * 128 + lg * 16;
      int swz = (krow & 7) << 4;
      bf16x8 kf0 = *(const bf16x8*)((const char*)Kl + (base ^ swz));
      bf16x8 kf1 = *(const bf16x8*)((const char*)Kl + ((base + 64) ^ swz));
      sa[kt] = mfma16(kf0, qf0, sa[kt]);
      sa[kt] = mfma16(kf1, qf1, sa[kt]);
    }

    // masked online softmax; lane owns q-row (lq), 16 keys across 4 tiles
    const int k0 = t * 64;
    float p[16];
    float pm = -1e30f;
#pragma unroll
    for (int kt = 0; kt < 4; ++kt) {
#pragma unroll
      for (int r = 0; r < 4; ++r) {
        int key = k0 + kt * 16 + lg * 4 + r;
        float sv = sa[kt][r] * 0.125f;
        sv = (key <= qrow) ? sv : -1e30f;
        p[kt * 4 + r] = sv;
        pm = fmaxf(pm, sv);
      }
    }
    pm = fmaxf(pm, __shfl_xor(pm, 16));
    pm = fmaxf(pm, __shfl_xor(pm, 32));
    float mnew = fmaxf(m_run, pm);
    float alpha = __expf(m_run - mnew);
    float rs = 0.f;
#pragma unroll
    for (int i = 0; i < 16; ++i) {
      p[i] = __expf(p[i] - mnew);
      rs += p[i];
    }
    rs += __shfl_xor(rs, 16);
    rs += __shfl_xor(rs, 32);
    l_run = l_run * alpha + rs;
    m_run = mnew;

#pragma unroll
    for (int r = 0; r < 4; ++r) {
      float ar = __shfl(alpha, lg * 4 + r);
#pragma unroll
      for (int dt = 0; dt < 4; ++dt) accO[dt][r] *= ar;
    }

    // P -> per-wave LDS (bf16, swizzled [q][k])
    {
      int swz = (lq & 7) << 4;
#pragma unroll
      for (int kt = 0; kt < 4; ++kt) {
#pragma unroll
        for (int r2 = 0; r2 < 2; ++r2) {
          u32 pk = (u32)f2bf(p[kt * 4 + r2 * 2]) | ((u32)f2bf(p[kt * 4 + r2 * 2 + 1]) << 16);
          int ad = (lq * 128 + (kt * 16 + lg * 4 + r2 * 2) * 2) ^ swz;
          *(u32*)((char*)Pl[w] + ad) = pk;
        }
      }
    }
    // PV: O[q][d] += P[q][k] * V[k][d], V from transposed tile
    {
      int swz = (lq & 7) << 4;
      bf16x8 pa0 = *(const bf16x8*)((const char*)Pl[w] + ((lq * 128 + lg * 16) ^ swz));
      bf16x8 pa1 = *(const bf16x8*)((const char*)Pl[w] + ((lq * 128 + 64 + lg * 16) ^ swz));
#pragma unroll
      for (int dt = 0; dt < 4; ++dt) {
        int vrow = dt * 16 + lq;
        int vb = vrow * 128 + lg * 16;
        int vs = (vrow & 7) << 4;
        bf16x8 v0 = *(const bf16x8*)((const char*)Vl + (vb ^ vs));
        bf16x8 v1 = *(const bf16x8*)((const char*)Vl + ((vb + 64) ^ vs));
        accO[dt] = mfma16(pa0, v0, accO[dt]);
        accO[dt] = mfma16(pa1, v1, accO[dt]);
      }
    }
    __syncthreads();
    kreg[0] = k2[0]; kreg[1] = k2[1]; vreg[0] = v2[0]; vreg[1] = v2[1];
  }

  const int b = bh >> 4, h = bh & 15;
#pragma unroll
  for (int r = 0; r < 4; ++r) {
    float lr = __shfl(l_run, lg * 4 + r);
    float inv = 1.f / (lr + 1e-9f);
    int qq = q0 + w * 16 + lg * 4 + r;
    u16* orow = ao + ((size_t)b * SEQ + qq) * D_MODEL + h * DK;
#pragma unroll
    for (int dt = 0; dt < 4; ++dt) orow[dt * 16 + lq] = f2bf(accO[dt][r] * inv);
  }
}

extern "C" void kernel_launch(void* const* d_in, const int* in_sizes, int n_in,
                              void* d_out, int out_size, void* d_ws, size_t ws_size,
                              hipStream_t stream) {
  const float* x = (const float*)d_in[0];
  const float* wq = (const float*)d_in[1];
  const float* wk = (const float*)d_in[2];
  const float* wv = (const float*)d_in[3];
  const float* wo = (const float*)d_in[4];
  float* out = (float*)d_out;
  char* ws = (char*)d_ws;

  u16* xb   = (u16*)(ws + 0);             // 8 MB
  u16* wqb  = (u16*)(ws + 8388608);       // 2 MB
  u16* wkb  = (u16*)(ws + 10485760);
  u16* wvb  = (u16*)(ws + 12582912);
  u16* wob  = (u16*)(ws + 14680064);
  u16* qkv  = (u16*)(ws + 16777216);      // 24 MB [4096][3072]
  u16* qhb  = (u16*)(ws + 41943040);      // 8 MB [32][2048][64]
  u16* khb  = (u16*)(ws + 50331648);      // 8 MB
  u16* vtb  = (u16*)(ws + 58720256);      // 8 MB [32][64][2048]
  u16* aob  = (u16*)(ws + 67108864);      // 8 MB [4096][1024]
  float* ct = (float*)(ws + 75497472);    // 256 KB
  float* st = (float*)(ws + 75759616);    // 256 KB

  k_cast<<<4096, 256, 0, stream>>>(x, wq, wk, wv, wo, xb, wqb, wkb, wvb, wob);
  k_tab<<<256, 256, 0, stream>>>(ct, st);
  k_gemm<true, false><<<dim3(32, 24), 256, 0, stream>>>(xb, wqb, wkb, wvb, qkv, nullptr, 3072);
  k_rope<<<dim3(2048, 2), 256, 0, stream>>>(qkv, ct, st, qhb, khb);
  k_vtrans<<<dim3(32, 32), 256, 0, stream>>>(qkv, vtb);
  k_attn<<<dim3(32, 32), 256, 0, stream>>>(qhb, khb, vtb, aob);
  k_gemm<false, true><<<dim3(32, 8), 256, 0, stream>>>(aob, wob, nullptr, nullptr, nullptr, out, 1024);
}

// Round 2
// 237.182 us; speedup vs baseline: 2.3648x; 2.3648x over previous
//
#include <hip/hip_runtime.h>
#include <stdint.h>

typedef unsigned short u16;
typedef unsigned int u32;
typedef __bf16 bf16x8 __attribute__((ext_vector_type(8)));
typedef float f32x4 __attribute__((ext_vector_type(4)));
typedef unsigned short u16x8 __attribute__((ext_vector_type(8)));

#define D_MODEL 1024
#define SEQ 2048
#define NH 16
#define DK 64
#define NROWS 4096  // B*S

static __device__ __forceinline__ u16 f2bf(float f) {
  u32 u = __float_as_uint(f);
  u = (u + 0x7FFFu + ((u >> 16) & 1u)) >> 16;
  return (u16)u;
}
static __device__ __forceinline__ float bf2f(u16 h) {
  return __uint_as_float(((u32)h) << 16);
}
static __device__ __forceinline__ f32x4 mfma16(bf16x8 a, bf16x8 b, f32x4 c) {
  return __builtin_amdgcn_mfma_f32_16x16x32_bf16(a, b, c, 0, 0, 0);
}
static __device__ __forceinline__ void gload16(const void* g, void* l) {
  __builtin_amdgcn_global_load_lds(
      (const __attribute__((address_space(1))) void*)g,
      (__attribute__((address_space(3))) void*)l, 16, 0, 0);
}

// ---------------- fp32 -> bf16 cast of x and the 4 weight matrices ----------------
__global__ __launch_bounds__(256) void k_cast(
    const float* __restrict__ x, const float* __restrict__ wq,
    const float* __restrict__ wk, const float* __restrict__ wv,
    const float* __restrict__ wo, u16* __restrict__ xb, u16* __restrict__ wqb,
    u16* __restrict__ wkb, u16* __restrict__ wvb, u16* __restrict__ wob) {
  size_t e = ((size_t)blockIdx.x * 256 + threadIdx.x) * 8;
  const float* s;
  u16* d;
  size_t off;
  if (e < (size_t)NROWS * D_MODEL) {
    s = x; d = xb; off = e;
  } else {
    size_t r = e - (size_t)NROWS * D_MODEL;
    unsigned wi = (unsigned)(r >> 20);
    off = r & 1048575u;
    s = wi == 0 ? wq : wi == 1 ? wk : wi == 2 ? wv : wo;
    d = wi == 0 ? wqb : wi == 1 ? wkb : wi == 2 ? wvb : wob;
  }
  float4 a = *(const float4*)(s + off);
  float4 b = *(const float4*)(s + off + 4);
  u16x8 o;
  o[0] = f2bf(a.x); o[1] = f2bf(a.y); o[2] = f2bf(a.z); o[3] = f2bf(a.w);
  o[4] = f2bf(b.x); o[5] = f2bf(b.y); o[6] = f2bf(b.z); o[7] = f2bf(b.w);
  *(u16x8*)(d + off) = o;
}

// ---------------- RoPE tables (fp64 on device -> fp32 tables) ----------------
__global__ __launch_bounds__(256) void k_tab(float* __restrict__ ct, float* __restrict__ st) {
  int i = blockIdx.x * 256 + threadIdx.x;  // 2048*32
  int s = i >> 5, p = i & 31;
  double ang = (double)s * pow(10000.0, -(double)p / 32.0);
  ct[i] = (float)cos(ang);
  st[i] = (float)sin(ang);
}

// ---------------- bf16 B^T GEMM: C[M,N] = A[M,K] * B'[N,K]^T, K=1024 ----------------
// m97 structure: 128x128 tile, global_load_lds(16B) staging, linear LDS,
// 2 barriers/K-step, 4 waves of 64x64, 16x16x32 MFMA.
template <bool MULTI, bool OUTF32>
__global__ __launch_bounds__(256, 1) void k_gemm(
    const u16* __restrict__ A, const u16* __restrict__ B0,
    const u16* __restrict__ B1, const u16* __restrict__ B2,
    u16* __restrict__ Cb, float* __restrict__ Cf, int ldc) {
  constexpr int K = 1024;
  const int mb = blockIdx.x, nb = blockIdx.y;
  const int tid = threadIdx.x;
  const int lane = tid & 63, w = tid >> 6;
  const int lq = lane & 15, lg = lane >> 4;
  const int wm = w >> 1, wn = w & 1;
  __shared__ __align__(16) u16 As[128 * 32];
  __shared__ __align__(16) u16 Bs[128 * 32];

  const u16* Bp;
  if (MULTI) {
    int sel = nb >> 3;
    Bp = sel == 0 ? B0 : (sel == 1 ? B1 : B2);
  } else {
    Bp = B0;
  }
  int nloc = MULTI ? (nb & 7) * 128 : nb * 128;
  const char* Ab = (const char*)A + (size_t)mb * 128 * 2048;
  const char* Bb = (const char*)Bp + (size_t)nloc * 2048;

  const int srow = tid >> 2;       // 0..63
  const int scb = (tid & 3) * 16;  // 0,16,32,48 byte col

  f32x4 zero4 = {0.f, 0.f, 0.f, 0.f};
  f32x4 acc[4][4];
#pragma unroll
  for (int i = 0; i < 4; ++i)
#pragma unroll
    for (int j = 0; j < 4; ++j) acc[i][j] = zero4;

  for (int k0 = 0; k0 < K; k0 += 32) {
#pragma unroll
    for (int c = 0; c < 2; ++c) {
      int o = c * 4096 + tid * 16;  // linear LDS byte offset == lane order
      const char* ga = Ab + (size_t)(c * 64 + srow) * 2048 + k0 * 2 + scb;
      const char* gb = Bb + (size_t)(c * 64 + srow) * 2048 + k0 * 2 + scb;
      gload16(ga, (char*)As + o);
      gload16(gb, (char*)Bs + o);
    }
    __syncthreads();  // drains DMA (vmcnt) + aligns waves
    bf16x8 af[4], bfr[4];
#pragma unroll
    for (int i = 0; i < 4; ++i) {
      af[i] = *(const bf16x8*)((const char*)As + (wm * 64 + i * 16 + lq) * 64 + lg * 16);
      bfr[i] = *(const bf16x8*)((const char*)Bs + (wn * 64 + i * 16 + lq) * 64 + lg * 16);
    }
#pragma unroll
    for (int i = 0; i < 4; ++i)
#pragma unroll
      for (int j = 0; j < 4; ++j) acc[i][j] = mfma16(af[i], bfr[j], acc[i][j]);
    __syncthreads();  // all reads done before next-tile DMA overwrites
  }

#pragma unroll
  for (int i = 0; i < 4; ++i) {
#pragma unroll
    for (int r = 0; r < 4; ++r) {
      size_t rowg = (size_t)(mb * 128 + wm * 64 + i * 16 + lg * 4 + r);
#pragma unroll
      for (int j = 0; j < 4; ++j) {
        int colg = nb * 128 + wn * 64 + j * 16 + lq;
        if (OUTF32)
          Cf[rowg * ldc + colg] = acc[i][j][r];
        else
          Cb[rowg * ldc + colg] = f2bf(acc[i][j][r]);
      }
    }
  }
}

// ---------------- RoPE apply + reshape to head-major [BH][S][64] ----------------
__global__ __launch_bounds__(256) void k_rope(const u16* __restrict__ qkv,
                                              const float* __restrict__ ct,
                                              const float* __restrict__ st,
                                              u16* __restrict__ qh, u16* __restrict__ kh) {
  int gi = blockIdx.x * 256 + threadIdx.x;  // 524288
  int row = gi >> 7;
  int col = (gi & 127) << 3;
  int h = col >> 6, d0 = col & 63;
  int b = row >> 11, s = row & 2047;
  const int srcoff = blockIdx.y ? 1024 : 0;
  u16x8 v = *(const u16x8*)(qkv + (size_t)row * 3072 + srcoff + col);
  const float* cp = ct + s * 32 + (d0 >> 1);
  const float* sp = st + s * 32 + (d0 >> 1);
  u16x8 o;
#pragma unroll
  for (int i = 0; i < 4; ++i) {
    float ev = bf2f(v[2 * i]), od = bf2f(v[2 * i + 1]);
    float c = cp[i], sn = sp[i];
    o[2 * i] = f2bf(ev * c - od * sn);
    o[2 * i + 1] = f2bf(ev * sn + od * c);
  }
  u16* dst = blockIdx.y ? kh : qh;
  *(u16x8*)(dst + (((size_t)(b * 16 + h) * SEQ + s) << 6) + d0) = o;
}

// ---------------- V transpose: qkv V cols -> Vt [BH][64][S] ----------------
__global__ __launch_bounds__(256) void k_vtrans(const u16* __restrict__ qkv,
                                                u16* __restrict__ vt) {
  __shared__ __align__(16) u16 t[64][72];
  int sb = blockIdx.x, bh = blockIdx.y;
  int b = bh >> 4, h = bh & 15;
  int tid = threadIdx.x;
#pragma unroll
  for (int c = 0; c < 2; ++c) {
    int o = tid * 8 + c * 2048;
    int r = o >> 6, d = o & 63;
    u16x8 v = *(const u16x8*)(qkv + (size_t)(b * SEQ + sb * 64 + r) * 3072 + 2048 + h * 64 + d);
    *(u16x8*)&t[r][d] = v;
  }
  __syncthreads();
#pragma unroll
  for (int c = 0; c < 2; ++c) {
    int o = tid * 8 + c * 2048;
    int d = o >> 6, si = o & 63;
    u16x8 v;
#pragma unroll
    for (int j = 0; j < 8; ++j) v[j] = t[si + j][d];
    *(u16x8*)(vt + ((size_t)bh * 64 + d) * SEQ + sb * 64 + si) = v;
  }
}

// ---------------- causal flash attention ----------------
// grid (16 qblocks of 128 rows, 32 bh); 4 waves x 2 strips x 16 q-rows;
// KV block 64; swapped QK^T; swizzled K/V/P LDS.
__global__ __launch_bounds__(256, 1) void k_attn(const u16* __restrict__ qh,
                                                 const u16* __restrict__ kh,
                                                 const u16* __restrict__ vt,
                                                 u16* __restrict__ ao) {
  const int qb = 15 - (int)blockIdx.x;  // heavy blocks first
  const int bh = blockIdx.y;
  const int tid = threadIdx.x;
  const int w = tid >> 6;
  const int lane = tid & 63;
  const int lq = lane & 15;
  const int lg = lane >> 4;

  __shared__ __align__(16) u16 Kl[64 * 64];
  __shared__ __align__(16) u16 Vl[64 * 64];
  __shared__ __align__(16) u16 Pl[4][2][16 * 64];

  const int q0 = qb * 128;
  const int qr0 = q0 + w * 32;

  int qrow[2];
  bf16x8 qf[2][2];
#pragma unroll
  for (int g = 0; g < 2; ++g) {
    qrow[g] = qr0 + g * 16 + lq;
    const u16* qptr = qh + ((size_t)bh * SEQ + qrow[g]) * DK + lg * 8;
    qf[g][0] = *(const bf16x8*)qptr;
    qf[g][1] = *(const bf16x8*)(qptr + 32);
  }

  f32x4 zero4 = {0.f, 0.f, 0.f, 0.f};
  f32x4 accO[2][4];
#pragma unroll
  for (int g = 0; g < 2; ++g)
#pragma unroll
    for (int dt = 0; dt < 4; ++dt) accO[g][dt] = zero4;
  float m_run[2] = {-1e30f, -1e30f};
  float l_run[2] = {0.f, 0.f};

  const int nkv = (qb + 1) * 2;
  const int srow = tid >> 3;       // 0..31
  const int scb = (tid & 7) * 16;  // byte col in 128B row

  uint4 kreg[2], vreg[2];
#pragma unroll
  for (int c = 0; c < 2; ++c) {
    int r = srow + c * 32;
    kreg[c] = *(const uint4*)((const char*)(kh + ((size_t)bh * SEQ + r) * DK) + scb);
    vreg[c] = *(const uint4*)((const char*)(vt + ((size_t)bh * DK + r) * SEQ) + scb);
  }

  for (int t = 0; t < nkv; ++t) {
#pragma unroll
    for (int c = 0; c < 2; ++c) {
      int r = srow + c * 32;
      int ad = (r * 128 + scb) ^ ((r & 7) << 4);
      *(uint4*)((char*)Kl + ad) = kreg[c];
      *(uint4*)((char*)Vl + ad) = vreg[c];
    }
    __syncthreads();

    uint4 k2[2], v2[2];
    if (t + 1 < nkv) {
      int k0n = (t + 1) * 64;
#pragma unroll
      for (int c = 0; c < 2; ++c) {
        int r = srow + c * 32;
        k2[c] = *(const uint4*)((const char*)(kh + ((size_t)bh * SEQ + k0n + r) * DK) + scb);
        v2[c] = *(const uint4*)((const char*)(vt + ((size_t)bh * DK + r) * SEQ + k0n) + scb);
      }
    } else {
      k2[0] = kreg[0]; k2[1] = kreg[1]; v2[0] = vreg[0]; v2[1] = vreg[1];
    }

    const int k0 = t * 64;
#pragma unroll
    for (int g = 0; g < 2; ++g) {
      if (k0 <= qr0 + g * 16 + 15) {  // strip has >=1 unmasked key (wave-uniform)
        // QK^T, swapped: D[key][q]
        f32x4 sa[4];
        sa[0] = zero4; sa[1] = zero4; sa[2] = zero4; sa[3] = zero4;
#pragma unroll
        for (int kt = 0; kt < 4; ++kt) {
          int krow = kt * 16 + lq;
          int base = krow * 128 + lg * 16;
          int swz = (krow & 7) << 4;
          bf16x8 kf0 = *(const bf16x8*)((const char*)Kl + (base ^ swz));
          bf16x8 kf1 = *(const bf16x8*)((const char*)Kl + ((base + 64) ^ swz));
          sa[kt] = mfma16(kf0, qf[g][0], sa[kt]);
          sa[kt] = mfma16(kf1, qf[g][1], sa[kt]);
        }

        // masked online softmax; lane owns q-row (lq), 16 keys across 4 tiles
        float p[16];
        float pm = -1e30f;
#pragma unroll
        for (int kt = 0; kt < 4; ++kt) {
#pragma unroll
          for (int r = 0; r < 4; ++r) {
            int key = k0 + kt * 16 + lg * 4 + r;
            float sv = sa[kt][r] * 0.125f;
            sv = (key <= qrow[g]) ? sv : -1e30f;
            p[kt * 4 + r] = sv;
            pm = fmaxf(pm, sv);
          }
        }
        pm = fmaxf(pm, __shfl_xor(pm, 16));
        pm = fmaxf(pm, __shfl_xor(pm, 32));
        float mnew = fmaxf(m_run[g], pm);
        float alpha = __expf(m_run[g] - mnew);
        float rs = 0.f;
#pragma unroll
        for (int i = 0; i < 16; ++i) {
          p[i] = __expf(p[i] - mnew);
          rs += p[i];
        }
        rs += __shfl_xor(rs, 16);
        rs += __shfl_xor(rs, 32);
        l_run[g] = l_run[g] * alpha + rs;
        m_run[g] = mnew;

#pragma unroll
        for (int r = 0; r < 4; ++r) {
          float ar = __shfl(alpha, lg * 4 + r);
#pragma unroll
          for (int dt = 0; dt < 4; ++dt) accO[g][dt][r] *= ar;
        }

        // P -> per-wave-strip LDS (bf16, swizzled [q][k])
        {
          int swz = (lq & 7) << 4;
#pragma unroll
          for (int kt = 0; kt < 4; ++kt) {
#pragma unroll
            for (int r2 = 0; r2 < 2; ++r2) {
              u32 pk = (u32)f2bf(p[kt * 4 + r2 * 2]) |
                       ((u32)f2bf(p[kt * 4 + r2 * 2 + 1]) << 16);
              int ad = (lq * 128 + (kt * 16 + lg * 4 + r2 * 2) * 2) ^ swz;
              *(u32*)((char*)Pl[w][g] + ad) = pk;
            }
          }
        }
        // PV: O[q][d] += P[q][k] * V[k][d], V from transposed tile
        {
          int swz = (lq & 7) << 4;
          bf16x8 pa0 = *(const bf16x8*)((const char*)Pl[w][g] + ((lq * 128 + lg * 16) ^ swz));
          bf16x8 pa1 = *(const bf16x8*)((const char*)Pl[w][g] + ((lq * 128 + 64 + lg * 16) ^ swz));
#pragma unroll
          for (int dt = 0; dt < 4; ++dt) {
            int vrow = dt * 16 + lq;
            int vb = vrow * 128 + lg * 16;
            int vs = (vrow & 7) << 4;
            bf16x8 v0 = *(const bf16x8*)((const char*)Vl + (vb ^ vs));
            bf16x8 v1 = *(const bf16x8*)((const char*)Vl + ((vb + 64) ^ vs));
            accO[g][dt] = mfma16(pa0, v0, accO[g][dt]);
            accO[g][dt] = mfma16(pa1, v1, accO[g][dt]);
          }
        }
      }
    }
    __syncthreads();
    kreg[0] = k2[0]; kreg[1] = k2[1]; vreg[0] = v2[0]; vreg[1] = v2[1];
  }

  const int b = bh >> 4, h = bh & 15;
#pragma unroll
  for (int g = 0; g < 2; ++g) {
#pragma unroll
    for (int r = 0; r < 4; ++r) {
      float lr = __shfl(l_run[g], lg * 4 + r);
      float inv = 1.f / (lr + 1e-9f);
      int qq = qr0 + g * 16 + lg * 4 + r;
      u16* orow = ao + ((size_t)b * SEQ + qq) * D_MODEL + h * DK;
#pragma unroll
      for (int dt = 0; dt < 4; ++dt) orow[dt * 16 + lq] = f2bf(accO[g][dt][r] * inv);
    }
  }
}

extern "C" void kernel_launch(void* const* d_in, const int* in_sizes, int n_in,
                              void* d_out, int out_size, void* d_ws, size_t ws_size,
                              hipStream_t stream) {
  const float* x = (const float*)d_in[0];
  const float* wq = (const float*)d_in[1];
  const float* wk = (const float*)d_in[2];
  const float* wv = (const float*)d_in[3];
  const float* wo = (const float*)d_in[4];
  float* out = (float*)d_out;
  char* ws = (char*)d_ws;

  u16* xb   = (u16*)(ws + 0);             // 8 MB
  u16* wqb  = (u16*)(ws + 8388608);       // 2 MB
  u16* wkb  = (u16*)(ws + 10485760);
  u16* wvb  = (u16*)(ws + 12582912);
  u16* wob  = (u16*)(ws + 14680064);
  u16* qkv  = (u16*)(ws + 16777216);      // 24 MB [4096][3072]
  u16* qhb  = (u16*)(ws + 41943040);      // 8 MB [32][2048][64]
  u16* khb  = (u16*)(ws + 50331648);      // 8 MB
  u16* vtb  = (u16*)(ws + 58720256);      // 8 MB [32][64][2048]
  u16* aob  = (u16*)(ws + 67108864);      // 8 MB [4096][1024]
  float* ct = (float*)(ws + 75497472);    // 256 KB
  float* st = (float*)(ws + 75759616);    // 256 KB

  k_cast<<<4096, 256, 0, stream>>>(x, wq, wk, wv, wo, xb, wqb, wkb, wvb, wob);
  k_tab<<<256, 256, 0, stream>>>(ct, st);
  k_gemm<true, false><<<dim3(32, 24), 256, 0, stream>>>(xb, wqb, wkb, wvb, qkv, nullptr, 3072);
  k_rope<<<dim3(2048, 2), 256, 0, stream>>>(qkv, ct, st, qhb, khb);
  k_vtrans<<<dim3(32, 32), 256, 0, stream>>>(qkv, vtb);
  k_attn<<<dim3(16, 32), 256, 0, stream>>>(qhb, khb, vtb, aob);
  k_gemm<false, true><<<dim3(32, 8), 256, 0, stream>>>(aob, wob, nullptr, nullptr, nullptr, out, 1024);
}

// Round 3
// 151.882 us; speedup vs baseline: 3.6929x; 1.5616x over previous
//
#include <hip/hip_runtime.h>
#include <stdint.h>

typedef unsigned short u16;
typedef unsigned int u32;
typedef __bf16 bf16x8 __attribute__((ext_vector_type(8)));
typedef float f32x4 __attribute__((ext_vector_type(4)));
typedef unsigned short u16x8 __attribute__((ext_vector_type(8)));

#define D_MODEL 1024
#define SEQ 2048
#define NH 16
#define DK 64
#define NROWS 4096  // B*S

static __device__ __forceinline__ u16 f2bf(float f) {
  u32 u = __float_as_uint(f);
  u = (u + 0x7FFFu + ((u >> 16) & 1u)) >> 16;
  return (u16)u;
}
static __device__ __forceinline__ float bf2f(u16 h) {
  return __uint_as_float(((u32)h) << 16);
}
static __device__ __forceinline__ f32x4 mfma16(bf16x8 a, bf16x8 b, f32x4 c) {
  return __builtin_amdgcn_mfma_f32_16x16x32_bf16(a, b, c, 0, 0, 0);
}
static __device__ __forceinline__ void gload16(const void* g, void* l) {
  __builtin_amdgcn_global_load_lds(
      (const __attribute__((address_space(1))) void*)g,
      (__attribute__((address_space(3))) void*)l, 16, 0, 0);
}

// ---------------- fp32 -> bf16 cast of x and the 4 weight matrices ----------------
__global__ __launch_bounds__(256) void k_cast(
    const float* __restrict__ x, const float* __restrict__ wq,
    const float* __restrict__ wk, const float* __restrict__ wv,
    const float* __restrict__ wo, u16* __restrict__ xb, u16* __restrict__ wqb,
    u16* __restrict__ wkb, u16* __restrict__ wvb, u16* __restrict__ wob) {
  size_t e = ((size_t)blockIdx.x * 256 + threadIdx.x) * 8;
  const float* s;
  u16* d;
  size_t off;
  if (e < (size_t)NROWS * D_MODEL) {
    s = x; d = xb; off = e;
  } else {
    size_t r = e - (size_t)NROWS * D_MODEL;
    unsigned wi = (unsigned)(r >> 20);
    off = r & 1048575u;
    s = wi == 0 ? wq : wi == 1 ? wk : wi == 2 ? wv : wo;
    d = wi == 0 ? wqb : wi == 1 ? wkb : wi == 2 ? wvb : wob;
  }
  float4 a = *(const float4*)(s + off);
  float4 b = *(const float4*)(s + off + 4);
  u16x8 o;
  o[0] = f2bf(a.x); o[1] = f2bf(a.y); o[2] = f2bf(a.z); o[3] = f2bf(a.w);
  o[4] = f2bf(b.x); o[5] = f2bf(b.y); o[6] = f2bf(b.z); o[7] = f2bf(b.w);
  *(u16x8*)(d + off) = o;
}

// ---------------- RoPE tables (fp64 on device -> fp32 tables) ----------------
__global__ __launch_bounds__(256) void k_tab(float* __restrict__ ct, float* __restrict__ st) {
  int i = blockIdx.x * 256 + threadIdx.x;  // 2048*32
  int s = i >> 5, p = i & 31;
  double ang = (double)s * pow(10000.0, -(double)p / 32.0);
  ct[i] = (float)cos(ang);
  st[i] = (float)sin(ang);
}

// ---------------- bf16 B^T GEMM: C[M,N] = A[M,K] * B'[N,K]^T, K=1024 ----------------
// m97 structure: 128x128 tile, global_load_lds(16B) staging, linear LDS,
// 2 barriers/K-step, 4 waves of 64x64, 16x16x32 MFMA.
template <bool MULTI, bool OUTF32>
__global__ __launch_bounds__(256, 1) void k_gemm(
    const u16* __restrict__ A, const u16* __restrict__ B0,
    const u16* __restrict__ B1, const u16* __restrict__ B2,
    u16* __restrict__ Cb, float* __restrict__ Cf, int ldc) {
  constexpr int K = 1024;
  const int mb = blockIdx.x, nb = blockIdx.y;
  const int tid = threadIdx.x;
  const int lane = tid & 63, w = tid >> 6;
  const int lq = lane & 15, lg = lane >> 4;
  const int wm = w >> 1, wn = w & 1;
  __shared__ __align__(16) u16 As[128 * 32];
  __shared__ __align__(16) u16 Bs[128 * 32];

  const u16* Bp;
  if (MULTI) {
    int sel = nb >> 3;
    Bp = sel == 0 ? B0 : (sel == 1 ? B1 : B2);
  } else {
    Bp = B0;
  }
  int nloc = MULTI ? (nb & 7) * 128 : nb * 128;
  const char* Ab = (const char*)A + (size_t)mb * 128 * 2048;
  const char* Bb = (const char*)Bp + (size_t)nloc * 2048;

  const int srow = tid >> 2;       // 0..63
  const int scb = (tid & 3) * 16;  // 0,16,32,48 byte col

  f32x4 zero4 = {0.f, 0.f, 0.f, 0.f};
  f32x4 acc[4][4];
#pragma unroll
  for (int i = 0; i < 4; ++i)
#pragma unroll
    for (int j = 0; j < 4; ++j) acc[i][j] = zero4;

  for (int k0 = 0; k0 < K; k0 += 32) {
#pragma unroll
    for (int c = 0; c < 2; ++c) {
      int o = c * 4096 + tid * 16;  // linear LDS byte offset == lane order
      const char* ga = Ab + (size_t)(c * 64 + srow) * 2048 + k0 * 2 + scb;
      const char* gb = Bb + (size_t)(c * 64 + srow) * 2048 + k0 * 2 + scb;
      gload16(ga, (char*)As + o);
      gload16(gb, (char*)Bs + o);
    }
    __syncthreads();  // drains DMA (vmcnt) + aligns waves
    bf16x8 af[4], bfr[4];
#pragma unroll
    for (int i = 0; i < 4; ++i) {
      af[i] = *(const bf16x8*)((const char*)As + (wm * 64 + i * 16 + lq) * 64 + lg * 16);
      bfr[i] = *(const bf16x8*)((const char*)Bs + (wn * 64 + i * 16 + lq) * 64 + lg * 16);
    }
#pragma unroll
    for (int i = 0; i < 4; ++i)
#pragma unroll
      for (int j = 0; j < 4; ++j) acc[i][j] = mfma16(af[i], bfr[j], acc[i][j]);
    __syncthreads();  // all reads done before next-tile DMA overwrites
  }

#pragma unroll
  for (int i = 0; i < 4; ++i) {
#pragma unroll
    for (int r = 0; r < 4; ++r) {
      size_t rowg = (size_t)(mb * 128 + wm * 64 + i * 16 + lg * 4 + r);
#pragma unroll
      for (int j = 0; j < 4; ++j) {
        int colg = nb * 128 + wn * 64 + j * 16 + lq;
        if (OUTF32)
          Cf[rowg * ldc + colg] = acc[i][j][r];
        else
          Cb[rowg * ldc + colg] = f2bf(acc[i][j][r]);
      }
    }
  }
}

// ---------------- RoPE apply + reshape to head-major [BH][S][64] ----------------
__global__ __launch_bounds__(256) void k_rope(const u16* __restrict__ qkv,
                                              const float* __restrict__ ct,
                                              const float* __restrict__ st,
                                              u16* __restrict__ qh, u16* __restrict__ kh) {
  int gi = blockIdx.x * 256 + threadIdx.x;  // 524288
  int row = gi >> 7;
  int col = (gi & 127) << 3;
  int h = col >> 6, d0 = col & 63;
  int b = row >> 11, s = row & 2047;
  const int srcoff = blockIdx.y ? 1024 : 0;
  u16x8 v = *(const u16x8*)(qkv + (size_t)row * 3072 + srcoff + col);
  const float* cp = ct + s * 32 + (d0 >> 1);
  const float* sp = st + s * 32 + (d0 >> 1);
  u16x8 o;
#pragma unroll
  for (int i = 0; i < 4; ++i) {
    float ev = bf2f(v[2 * i]), od = bf2f(v[2 * i + 1]);
    float c = cp[i], sn = sp[i];
    o[2 * i] = f2bf(ev * c - od * sn);
    o[2 * i + 1] = f2bf(ev * sn + od * c);
  }
  u16* dst = blockIdx.y ? kh : qh;
  *(u16x8*)(dst + (((size_t)(b * 16 + h) * SEQ + s) << 6) + d0) = o;
}

// ---------------- V transpose: qkv V cols -> Vt [BH][64][S] ----------------
__global__ __launch_bounds__(256) void k_vtrans(const u16* __restrict__ qkv,
                                                u16* __restrict__ vt) {
  __shared__ __align__(16) u16 t[64][72];
  int sb = blockIdx.x, bh = blockIdx.y;
  int b = bh >> 4, h = bh & 15;
  int tid = threadIdx.x;
#pragma unroll
  for (int c = 0; c < 2; ++c) {
    int o = tid * 8 + c * 2048;
    int r = o >> 6, d = o & 63;
    u16x8 v = *(const u16x8*)(qkv + (size_t)(b * SEQ + sb * 64 + r) * 3072 + 2048 + h * 64 + d);
    *(u16x8*)&t[r][d] = v;
  }
  __syncthreads();
#pragma unroll
  for (int c = 0; c < 2; ++c) {
    int o = tid * 8 + c * 2048;
    int d = o >> 6, si = o & 63;
    u16x8 v;
#pragma unroll
    for (int j = 0; j < 8; ++j) v[j] = t[si + j][d];
    *(u16x8*)(vt + ((size_t)bh * 64 + d) * SEQ + sb * 64 + si) = v;
  }
}

// ---------------- causal flash attention ----------------
// grid (16 qblocks of 128 rows, 32 bh); 8 waves x 16 q-rows (512 threads);
// KV block 64; swapped QK^T; swizzled K/V/P LDS.
__global__ __launch_bounds__(512, 2) void k_attn(const u16* __restrict__ qh,
                                                 const u16* __restrict__ kh,
                                                 const u16* __restrict__ vt,
                                                 u16* __restrict__ ao) {
  const int qb = 15 - (int)blockIdx.x;  // heavy blocks first
  const int bh = blockIdx.y;
  const int tid = threadIdx.x;
  const int w = tid >> 6;  // 0..7
  const int lane = tid & 63;
  const int lq = lane & 15;
  const int lg = lane >> 4;

  __shared__ __align__(16) u16 Kl[64 * 64];
  __shared__ __align__(16) u16 Vl[64 * 64];
  __shared__ __align__(16) u16 Pl[8][16 * 64];

  const int q0 = qb * 128;
  const int qtop = q0 + w * 16;       // this wave's strip
  const int qrow = qtop + lq;

  const u16* qptr = qh + ((size_t)bh * SEQ + qrow) * DK + lg * 8;
  bf16x8 qf0 = *(const bf16x8*)qptr;
  bf16x8 qf1 = *(const bf16x8*)(qptr + 32);

  f32x4 zero4 = {0.f, 0.f, 0.f, 0.f};
  f32x4 accO[4];
  accO[0] = zero4; accO[1] = zero4; accO[2] = zero4; accO[3] = zero4;
  float m_run = -1e30f, l_run = 0.f;

  const int nkv = (qb + 1) * 2;
  const int srow = tid >> 3;       // 0..63 (one row per thread)
  const int scb = (tid & 7) * 16;  // byte col in 128B row

  uint4 kreg, vreg;
  kreg = *(const uint4*)((const char*)(kh + ((size_t)bh * SEQ + srow) * DK) + scb);
  vreg = *(const uint4*)((const char*)(vt + ((size_t)bh * DK + srow) * SEQ) + scb);

  for (int t = 0; t < nkv; ++t) {
    {
      int ad = (srow * 128 + scb) ^ ((srow & 7) << 4);
      *(uint4*)((char*)Kl + ad) = kreg;
      *(uint4*)((char*)Vl + ad) = vreg;
    }
    __syncthreads();

    uint4 k2, v2;
    if (t + 1 < nkv) {
      int k0n = (t + 1) * 64;
      k2 = *(const uint4*)((const char*)(kh + ((size_t)bh * SEQ + k0n + srow) * DK) + scb);
      v2 = *(const uint4*)((const char*)(vt + ((size_t)bh * DK + srow) * SEQ + k0n) + scb);
    } else {
      k2 = kreg; v2 = vreg;
    }

    const int k0 = t * 64;
    if (k0 <= qtop + 15) {  // strip has >=1 unmasked key (wave-uniform)
      // QK^T, swapped: D[key][q]
      f32x4 sa[4];
      sa[0] = zero4; sa[1] = zero4; sa[2] = zero4; sa[3] = zero4;
#pragma unroll
      for (int kt = 0; kt < 4; ++kt) {
        int krow = kt * 16 + lq;
        int base = krow * 128 + lg * 16;
        int swz = (krow & 7) << 4;
        bf16x8 kf0 = *(const bf16x8*)((const char*)Kl + (base ^ swz));
        bf16x8 kf1 = *(const bf16x8*)((const char*)Kl + ((base + 64) ^ swz));
        sa[kt] = mfma16(kf0, qf0, sa[kt]);
        sa[kt] = mfma16(kf1, qf1, sa[kt]);
      }

      // masked online softmax; lane owns q-row (lq), 16 keys across 4 tiles
      float p[16];
      float pm = -1e30f;
#pragma unroll
      for (int kt = 0; kt < 4; ++kt) {
#pragma unroll
        for (int r = 0; r < 4; ++r) {
          int key = k0 + kt * 16 + lg * 4 + r;
          float sv = sa[kt][r] * 0.125f;
          sv = (key <= qrow) ? sv : -1e30f;
          p[kt * 4 + r] = sv;
          pm = fmaxf(pm, sv);
        }
      }
      pm = fmaxf(pm, __shfl_xor(pm, 16));
      pm = fmaxf(pm, __shfl_xor(pm, 32));
      float mnew = fmaxf(m_run, pm);
      float alpha = __expf(m_run - mnew);
      float rs = 0.f;
#pragma unroll
      for (int i = 0; i < 16; ++i) {
        p[i] = __expf(p[i] - mnew);
        rs += p[i];
      }
      rs += __shfl_xor(rs, 16);
      rs += __shfl_xor(rs, 32);
      l_run = l_run * alpha + rs;
      m_run = mnew;

#pragma unroll
      for (int r = 0; r < 4; ++r) {
        float ar = __shfl(alpha, lg * 4 + r);
#pragma unroll
        for (int dt = 0; dt < 4; ++dt) accO[dt][r] *= ar;
      }

      // P -> per-wave LDS (bf16, swizzled [q][k])
      {
        int swz = (lq & 7) << 4;
#pragma unroll
        for (int kt = 0; kt < 4; ++kt) {
#pragma unroll
          for (int r2 = 0; r2 < 2; ++r2) {
            u32 pk = (u32)f2bf(p[kt * 4 + r2 * 2]) |
                     ((u32)f2bf(p[kt * 4 + r2 * 2 + 1]) << 16);
            int ad = (lq * 128 + (kt * 16 + lg * 4 + r2 * 2) * 2) ^ swz;
            *(u32*)((char*)Pl[w] + ad) = pk;
          }
        }
      }
      // PV: O[q][d] += P[q][k] * V[k][d], V from transposed tile
      {
        int swz = (lq & 7) << 4;
        bf16x8 pa0 = *(const bf16x8*)((const char*)Pl[w] + ((lq * 128 + lg * 16) ^ swz));
        bf16x8 pa1 = *(const bf16x8*)((const char*)Pl[w] + ((lq * 128 + 64 + lg * 16) ^ swz));
#pragma unroll
        for (int dt = 0; dt < 4; ++dt) {
          int vrow = dt * 16 + lq;
          int vb = vrow * 128 + lg * 16;
          int vs = (vrow & 7) << 4;
          bf16x8 v0 = *(const bf16x8*)((const char*)Vl + (vb ^ vs));
          bf16x8 v1 = *(const bf16x8*)((const char*)Vl + ((vb + 64) ^ vs));
          accO[dt] = mfma16(pa0, v0, accO[dt]);
          accO[dt] = mfma16(pa1, v1, accO[dt]);
        }
      }
    }
    __syncthreads();
    kreg = k2; vreg = v2;
  }

  const int b = bh >> 4, h = bh & 15;
#pragma unroll
  for (int r = 0; r < 4; ++r) {
    float lr = __shfl(l_run, lg * 4 + r);
    float inv = 1.f / (lr + 1e-9f);
    int qq = qtop + lg * 4 + r;
    u16* orow = ao + ((size_t)b * SEQ + qq) * D_MODEL + h * DK;
#pragma unroll
    for (int dt = 0; dt < 4; ++dt) orow[dt * 16 + lq] = f2bf(accO[dt][r] * inv);
  }
}

extern "C" void kernel_launch(void* const* d_in, const int* in_sizes, int n_in,
                              void* d_out, int out_size, void* d_ws, size_t ws_size,
                              hipStream_t stream) {
  const float* x = (const float*)d_in[0];
  const float* wq = (const float*)d_in[1];
  const float* wk = (const float*)d_in[2];
  const float* wv = (const float*)d_in[3];
  const float* wo = (const float*)d_in[4];
  float* out = (float*)d_out;
  char* ws = (char*)d_ws;

  u16* xb   = (u16*)(ws + 0);             // 8 MB
  u16* wqb  = (u16*)(ws + 8388608);       // 2 MB
  u16* wkb  = (u16*)(ws + 10485760);
  u16* wvb  = (u16*)(ws + 12582912);
  u16* wob  = (u16*)(ws + 14680064);
  u16* qkv  = (u16*)(ws + 16777216);      // 24 MB [4096][3072]
  u16* qhb  = (u16*)(ws + 41943040);      // 8 MB [32][2048][64]
  u16* khb  = (u16*)(ws + 50331648);      // 8 MB
  u16* vtb  = (u16*)(ws + 58720256);      // 8 MB [32][64][2048]
  u16* aob  = (u16*)(ws + 67108864);      // 8 MB [4096][1024]
  float* ct = (float*)(ws + 75497472);    // 256 KB
  float* st = (float*)(ws + 75759616);    // 256 KB

  k_cast<<<4096, 256, 0, stream>>>(x, wq, wk, wv, wo, xb, wqb, wkb, wvb, wob);
  k_tab<<<256, 256, 0, stream>>>(ct, st);
  k_gemm<true, false><<<dim3(32, 24), 256, 0, stream>>>(xb, wqb, wkb, wvb, qkv, nullptr, 3072);
  k_rope<<<dim3(2048, 2), 256, 0, stream>>>(qkv, ct, st, qhb, khb);
  k_vtrans<<<dim3(32, 32), 256, 0, stream>>>(qkv, vtb);
  k_attn<<<dim3(16, 32), 512, 0, stream>>>(qhb, khb, vtb, aob);
  k_gemm<false, true><<<dim3(32, 8), 256, 0, stream>>>(aob, wob, nullptr, nullptr, nullptr, out, 1024);
}

// Round 4
// 140.566 us; speedup vs baseline: 3.9902x; 1.0805x over previous
//
#include <hip/hip_runtime.h>
#include <stdint.h>

typedef unsigned short u16;
typedef unsigned int u32;
typedef __bf16 bf16x8 __attribute__((ext_vector_type(8)));
typedef float f32x4 __attribute__((ext_vector_type(4)));
typedef unsigned short u16x8 __attribute__((ext_vector_type(8)));

#define D_MODEL 1024
#define SEQ 2048
#define NH 16
#define DK 64
#define NROWS 4096  // B*S

static __device__ __forceinline__ u16 f2bf(float f) {
  u32 u = __float_as_uint(f);
  u = (u + 0x7FFFu + ((u >> 16) & 1u)) >> 16;
  return (u16)u;
}
static __device__ __forceinline__ float bf2f(u16 h) {
  return __uint_as_float(((u32)h) << 16);
}
static __device__ __forceinline__ f32x4 mfma16(bf16x8 a, bf16x8 b, f32x4 c) {
  return __builtin_amdgcn_mfma_f32_16x16x32_bf16(a, b, c, 0, 0, 0);
}
static __device__ __forceinline__ void gload16(const void* g, void* l) {
  __builtin_amdgcn_global_load_lds(
      (const __attribute__((address_space(1))) void*)g,
      (__attribute__((address_space(3))) void*)l, 16, 0, 0);
}

// ---------------- fp32 -> bf16 cast of x and the 4 weight matrices ----------------
__global__ __launch_bounds__(256) void k_cast(
    const float* __restrict__ x, const float* __restrict__ wq,
    const float* __restrict__ wk, const float* __restrict__ wv,
    const float* __restrict__ wo, u16* __restrict__ xb, u16* __restrict__ wqb,
    u16* __restrict__ wkb, u16* __restrict__ wvb, u16* __restrict__ wob) {
  size_t e = ((size_t)blockIdx.x * 256 + threadIdx.x) * 8;
  const float* s;
  u16* d;
  size_t off;
  if (e < (size_t)NROWS * D_MODEL) {
    s = x; d = xb; off = e;
  } else {
    size_t r = e - (size_t)NROWS * D_MODEL;
    unsigned wi = (unsigned)(r >> 20);
    off = r & 1048575u;
    s = wi == 0 ? wq : wi == 1 ? wk : wi == 2 ? wv : wo;
    d = wi == 0 ? wqb : wi == 1 ? wkb : wi == 2 ? wvb : wob;
  }
  float4 a = *(const float4*)(s + off);
  float4 b = *(const float4*)(s + off + 4);
  u16x8 o;
  o[0] = f2bf(a.x); o[1] = f2bf(a.y); o[2] = f2bf(a.z); o[3] = f2bf(a.w);
  o[4] = f2bf(b.x); o[5] = f2bf(b.y); o[6] = f2bf(b.z); o[7] = f2bf(b.w);
  *(u16x8*)(d + off) = o;
}

// ---------------- RoPE tables (fp64 on device -> fp32 tables) ----------------
__global__ __launch_bounds__(256) void k_tab(float* __restrict__ ct, float* __restrict__ st) {
  int i = blockIdx.x * 256 + threadIdx.x;  // 2048*32
  int s = i >> 5, p = i & 31;
  double ang = (double)s * pow(10000.0, -(double)p / 32.0);
  ct[i] = (float)cos(ang);
  st[i] = (float)sin(ang);
}

// ---------------- bf16 B^T GEMM: C[M,N] = A[M,K] * B'[N,K]^T, K=1024 ----------------
// m97 structure: 128x128 tile, global_load_lds(16B) staging, linear LDS,
// 2 barriers/K-step, 4 waves of 64x64, 16x16x32 MFMA.
template <bool MULTI, bool OUTF32>
__global__ __launch_bounds__(256, 1) void k_gemm(
    const u16* __restrict__ A, const u16* __restrict__ B0,
    const u16* __restrict__ B1, const u16* __restrict__ B2,
    u16* __restrict__ Cb, float* __restrict__ Cf, int ldc) {
  constexpr int K = 1024;
  const int mb = blockIdx.x, nb = blockIdx.y;
  const int tid = threadIdx.x;
  const int lane = tid & 63, w = tid >> 6;
  const int lq = lane & 15, lg = lane >> 4;
  const int wm = w >> 1, wn = w & 1;
  __shared__ __align__(16) u16 As[128 * 32];
  __shared__ __align__(16) u16 Bs[128 * 32];

  const u16* Bp;
  if (MULTI) {
    int sel = nb >> 3;
    Bp = sel == 0 ? B0 : (sel == 1 ? B1 : B2);
  } else {
    Bp = B0;
  }
  int nloc = MULTI ? (nb & 7) * 128 : nb * 128;
  const char* Ab = (const char*)A + (size_t)mb * 128 * 2048;
  const char* Bb = (const char*)Bp + (size_t)nloc * 2048;

  const int srow = tid >> 2;       // 0..63
  const int scb = (tid & 3) * 16;  // 0,16,32,48 byte col

  f32x4 zero4 = {0.f, 0.f, 0.f, 0.f};
  f32x4 acc[4][4];
#pragma unroll
  for (int i = 0; i < 4; ++i)
#pragma unroll
    for (int j = 0; j < 4; ++j) acc[i][j] = zero4;

  for (int k0 = 0; k0 < K; k0 += 32) {
#pragma unroll
    for (int c = 0; c < 2; ++c) {
      int o = c * 4096 + tid * 16;  // linear LDS byte offset == lane order
      const char* ga = Ab + (size_t)(c * 64 + srow) * 2048 + k0 * 2 + scb;
      const char* gb = Bb + (size_t)(c * 64 + srow) * 2048 + k0 * 2 + scb;
      gload16(ga, (char*)As + o);
      gload16(gb, (char*)Bs + o);
    }
    __syncthreads();  // drains DMA (vmcnt) + aligns waves
    bf16x8 af[4], bfr[4];
#pragma unroll
    for (int i = 0; i < 4; ++i) {
      af[i] = *(const bf16x8*)((const char*)As + (wm * 64 + i * 16 + lq) * 64 + lg * 16);
      bfr[i] = *(const bf16x8*)((const char*)Bs + (wn * 64 + i * 16 + lq) * 64 + lg * 16);
    }
#pragma unroll
    for (int i = 0; i < 4; ++i)
#pragma unroll
      for (int j = 0; j < 4; ++j) acc[i][j] = mfma16(af[i], bfr[j], acc[i][j]);
    __syncthreads();  // all reads done before next-tile DMA overwrites
  }

#pragma unroll
  for (int i = 0; i < 4; ++i) {
#pragma unroll
    for (int r = 0; r < 4; ++r) {
      size_t rowg = (size_t)(mb * 128 + wm * 64 + i * 16 + lg * 4 + r);
#pragma unroll
      for (int j = 0; j < 4; ++j) {
        int colg = nb * 128 + wn * 64 + j * 16 + lq;
        if (OUTF32)
          Cf[rowg * ldc + colg] = acc[i][j][r];
        else
          Cb[rowg * ldc + colg] = f2bf(acc[i][j][r]);
      }
    }
  }
}

// ---------------- RoPE apply + reshape to head-major [BH][S][64] ----------------
__global__ __launch_bounds__(256) void k_rope(const u16* __restrict__ qkv,
                                              const float* __restrict__ ct,
                                              const float* __restrict__ st,
                                              u16* __restrict__ qh, u16* __restrict__ kh) {
  int gi = blockIdx.x * 256 + threadIdx.x;  // 524288
  int row = gi >> 7;
  int col = (gi & 127) << 3;
  int h = col >> 6, d0 = col & 63;
  int b = row >> 11, s = row & 2047;
  const int srcoff = blockIdx.y ? 1024 : 0;
  u16x8 v = *(const u16x8*)(qkv + (size_t)row * 3072 + srcoff + col);
  const float* cp = ct + s * 32 + (d0 >> 1);
  const float* sp = st + s * 32 + (d0 >> 1);
  u16x8 o;
#pragma unroll
  for (int i = 0; i < 4; ++i) {
    float ev = bf2f(v[2 * i]), od = bf2f(v[2 * i + 1]);
    float c = cp[i], sn = sp[i];
    o[2 * i] = f2bf(ev * c - od * sn);
    o[2 * i + 1] = f2bf(ev * sn + od * c);
  }
  u16* dst = blockIdx.y ? kh : qh;
  *(u16x8*)(dst + (((size_t)(b * 16 + h) * SEQ + s) << 6) + d0) = o;
}

// ---------------- V transpose: qkv V cols -> Vt [BH][64][S] ----------------
__global__ __launch_bounds__(256) void k_vtrans(const u16* __restrict__ qkv,
                                                u16* __restrict__ vt) {
  __shared__ __align__(16) u16 t[64][72];
  int sb = blockIdx.x, bh = blockIdx.y;
  int b = bh >> 4, h = bh & 15;
  int tid = threadIdx.x;
#pragma unroll
  for (int c = 0; c < 2; ++c) {
    int o = tid * 8 + c * 2048;
    int r = o >> 6, d = o & 63;
    u16x8 v = *(const u16x8*)(qkv + (size_t)(b * SEQ + sb * 64 + r) * 3072 + 2048 + h * 64 + d);
    *(u16x8*)&t[r][d] = v;
  }
  __syncthreads();
#pragma unroll
  for (int c = 0; c < 2; ++c) {
    int o = tid * 8 + c * 2048;
    int d = o >> 6, si = o & 63;
    u16x8 v;
#pragma unroll
    for (int j = 0; j < 8; ++j) v[j] = t[si + j][d];
    *(u16x8*)(vt + ((size_t)bh * 64 + d) * SEQ + sb * 64 + si) = v;
  }
}

// ---------------- causal flash attention ----------------
// grid (16 qblocks of 128 rows, 32 bh); 8 waves x 16 q-rows (512 threads);
// KV block 64; swapped QK^T; swizzled K/V/P LDS.
// VALU diet: exp2-domain softmax, cvt_pk bf16 repack, defer-max (THR=8 log2),
// setprio around MFMA. Interleaved qb order for pair balance.
__global__ __launch_bounds__(512, 2) void k_attn(const u16* __restrict__ qh,
                                                 const u16* __restrict__ kh,
                                                 const u16* __restrict__ vt,
                                                 u16* __restrict__ ao) {
  const int xb_ = (int)blockIdx.x;
  // order: 15,0,14,1,13,2,... adjacent pairs sum to 34 kv-tiles (balance)
  const int qb = (xb_ & 1) ? (xb_ >> 1) : (15 - (xb_ >> 1));
  const int bh = blockIdx.y;
  const int tid = threadIdx.x;
  const int w = tid >> 6;  // 0..7
  const int lane = tid & 63;
  const int lq = lane & 15;
  const int lg = lane >> 4;

  __shared__ __align__(16) u16 Kl[64 * 64];
  __shared__ __align__(16) u16 Vl[64 * 64];
  __shared__ __align__(16) u16 Pl[8][16 * 64];

  const int q0 = qb * 128;
  const int qtop = q0 + w * 16;  // this wave's strip
  const int qrow = qtop + lq;

  const u16* qptr = qh + ((size_t)bh * SEQ + qrow) * DK + lg * 8;
  bf16x8 qf0 = *(const bf16x8*)qptr;
  bf16x8 qf1 = *(const bf16x8*)(qptr + 32);

  f32x4 zero4 = {0.f, 0.f, 0.f, 0.f};
  f32x4 accO[4];
  accO[0] = zero4; accO[1] = zero4; accO[2] = zero4; accO[3] = zero4;
  float m_run = -1e30f, l_run = 0.f;
  const float SCL = 0.180336880f;  // 0.125 * log2(e): exp2 domain

  const int nkv = (qb + 1) * 2;
  const int srow = tid >> 3;       // 0..63 (one row per thread)
  const int scb = (tid & 7) * 16;  // byte col in 128B row

  uint4 kreg, vreg;
  kreg = *(const uint4*)((const char*)(kh + ((size_t)bh * SEQ + srow) * DK) + scb);
  vreg = *(const uint4*)((const char*)(vt + ((size_t)bh * DK + srow) * SEQ) + scb);

  for (int t = 0; t < nkv; ++t) {
    {
      int ad = (srow * 128 + scb) ^ ((srow & 7) << 4);
      *(uint4*)((char*)Kl + ad) = kreg;
      *(uint4*)((char*)Vl + ad) = vreg;
    }
    __syncthreads();

    uint4 k2, v2;
    if (t + 1 < nkv) {
      int k0n = (t + 1) * 64;
      k2 = *(const uint4*)((const char*)(kh + ((size_t)bh * SEQ + k0n + srow) * DK) + scb);
      v2 = *(const uint4*)((const char*)(vt + ((size_t)bh * DK + srow) * SEQ + k0n) + scb);
    } else {
      k2 = kreg; v2 = vreg;
    }

    const int k0 = t * 64;
    if (k0 <= qtop + 15) {  // strip has >=1 unmasked key (wave-uniform)
      // QK^T, swapped: D[key][q]
      f32x4 sa[4];
      sa[0] = zero4; sa[1] = zero4; sa[2] = zero4; sa[3] = zero4;
      __builtin_amdgcn_s_setprio(1);
#pragma unroll
      for (int kt = 0; kt < 4; ++kt) {
        int krow = kt * 16 + lq;
        int base = krow * 128 + lg * 16;
        int swz = (krow & 7) << 4;
        bf16x8 kf0 = *(const bf16x8*)((const char*)Kl + (base ^ swz));
        bf16x8 kf1 = *(const bf16x8*)((const char*)Kl + ((base + 64) ^ swz));
        sa[kt] = mfma16(kf0, qf0, sa[kt]);
        sa[kt] = mfma16(kf1, qf1, sa[kt]);
      }
      __builtin_amdgcn_s_setprio(0);

      // masked online softmax (exp2 domain); lane owns q-row lq
      float p[16];
      float pm = -1e30f;
#pragma unroll
      for (int kt = 0; kt < 4; ++kt) {
#pragma unroll
        for (int r = 0; r < 4; ++r) {
          int key = k0 + kt * 16 + lg * 4 + r;
          float sv = sa[kt][r] * SCL;
          sv = (key <= qrow) ? sv : -1e30f;
          p[kt * 4 + r] = sv;
          pm = fmaxf(pm, sv);
        }
      }
      pm = fmaxf(pm, __shfl_xor(pm, 16));
      pm = fmaxf(pm, __shfl_xor(pm, 32));
      const bool resc = __any(pm > m_run + 8.0f);  // defer-max, wave-uniform
      float mnew = resc ? fmaxf(m_run, pm) : m_run;
      float rs = 0.f;
#pragma unroll
      for (int i = 0; i < 16; ++i) {
        p[i] = __builtin_amdgcn_exp2f(p[i] - mnew);
        rs += p[i];
      }
      rs += __shfl_xor(rs, 16);
      rs += __shfl_xor(rs, 32);
      if (resc) {
        float alpha = __builtin_amdgcn_exp2f(m_run - mnew);
        l_run = l_run * alpha + rs;
        m_run = mnew;
#pragma unroll
        for (int r = 0; r < 4; ++r) {
          float ar = __shfl(alpha, lg * 4 + r);
#pragma unroll
          for (int dt = 0; dt < 4; ++dt) accO[dt][r] *= ar;
        }
      } else {
        l_run += rs;
      }

      // P -> per-wave LDS (bf16 via v_cvt_pk, swizzled [q][k])
      {
        int swz = (lq & 7) << 4;
#pragma unroll
        for (int kt = 0; kt < 4; ++kt) {
          u32 w0, w1;
          asm("v_cvt_pk_bf16_f32 %0, %1, %2"
              : "=v"(w0) : "v"(p[kt * 4 + 0]), "v"(p[kt * 4 + 1]));
          asm("v_cvt_pk_bf16_f32 %0, %1, %2"
              : "=v"(w1) : "v"(p[kt * 4 + 2]), "v"(p[kt * 4 + 3]));
          int a0 = (lq * 128 + (kt * 16 + lg * 4) * 2) ^ swz;
          int a1 = (lq * 128 + (kt * 16 + lg * 4 + 2) * 2) ^ swz;
          *(u32*)((char*)Pl[w] + a0) = w0;
          *(u32*)((char*)Pl[w] + a1) = w1;
        }
      }
      // PV: O[q][d] += P[q][k] * V[k][d], V from transposed tile
      {
        int swz = (lq & 7) << 4;
        bf16x8 pa0 = *(const bf16x8*)((const char*)Pl[w] + ((lq * 128 + lg * 16) ^ swz));
        bf16x8 pa1 = *(const bf16x8*)((const char*)Pl[w] + ((lq * 128 + 64 + lg * 16) ^ swz));
        __builtin_amdgcn_s_setprio(1);
#pragma unroll
        for (int dt = 0; dt < 4; ++dt) {
          int vrow = dt * 16 + lq;
          int vb = vrow * 128 + lg * 16;
          int vs = (vrow & 7) << 4;
          bf16x8 v0 = *(const bf16x8*)((const char*)Vl + (vb ^ vs));
          bf16x8 v1 = *(const bf16x8*)((const char*)Vl + ((vb + 64) ^ vs));
          accO[dt] = mfma16(pa0, v0, accO[dt]);
          accO[dt] = mfma16(pa1, v1, accO[dt]);
        }
        __builtin_amdgcn_s_setprio(0);
      }
    }
    __syncthreads();
    kreg = k2; vreg = v2;
  }

  const int b = bh >> 4, h = bh & 15;
#pragma unroll
  for (int r = 0; r < 4; ++r) {
    float lr = __shfl(l_run, lg * 4 + r);
    float inv = 1.f / (lr + 1e-9f);
    int qq = qtop + lg * 4 + r;
    u16* orow = ao + ((size_t)b * SEQ + qq) * D_MODEL + h * DK;
#pragma unroll
    for (int dt = 0; dt < 4; ++dt) orow[dt * 16 + lq] = f2bf(accO[dt][r] * inv);
  }
}

extern "C" void kernel_launch(void* const* d_in, const int* in_sizes, int n_in,
                              void* d_out, int out_size, void* d_ws, size_t ws_size,
                              hipStream_t stream) {
  const float* x = (const float*)d_in[0];
  const float* wq = (const float*)d_in[1];
  const float* wk = (const float*)d_in[2];
  const float* wv = (const float*)d_in[3];
  const float* wo = (const float*)d_in[4];
  float* out = (float*)d_out;
  char* ws = (char*)d_ws;

  u16* xb   = (u16*)(ws + 0);             // 8 MB
  u16* wqb  = (u16*)(ws + 8388608);       // 2 MB
  u16* wkb  = (u16*)(ws + 10485760);
  u16* wvb  = (u16*)(ws + 12582912);
  u16* wob  = (u16*)(ws + 14680064);
  u16* qkv  = (u16*)(ws + 16777216);      // 24 MB [4096][3072]
  u16* qhb  = (u16*)(ws + 41943040);      // 8 MB [32][2048][64]
  u16* khb  = (u16*)(ws + 50331648);      // 8 MB
  u16* vtb  = (u16*)(ws + 58720256);      // 8 MB [32][64][2048]
  u16* aob  = (u16*)(ws + 67108864);      // 8 MB [4096][1024]
  float* ct = (float*)(ws + 75497472);    // 256 KB
  float* st = (float*)(ws + 75759616);    // 256 KB

  k_cast<<<4096, 256, 0, stream>>>(x, wq, wk, wv, wo, xb, wqb, wkb, wvb, wob);
  k_tab<<<256, 256, 0, stream>>>(ct, st);
  k_gemm<true, false><<<dim3(32, 24), 256, 0, stream>>>(xb, wqb, wkb, wvb, qkv, nullptr, 3072);
  k_rope<<<dim3(2048, 2), 256, 0, stream>>>(qkv, ct, st, qhb, khb);
  k_vtrans<<<dim3(32, 32), 256, 0, stream>>>(qkv, vtb);
  k_attn<<<dim3(16, 32), 512, 0, stream>>>(qhb, khb, vtb, aob);
  k_gemm<false, true><<<dim3(32, 8), 256, 0, stream>>>(aob, wob, nullptr, nullptr, nullptr, out, 1024);
}

// Round 5
// 132.131 us; speedup vs baseline: 4.2450x; 1.0638x over previous
//
#include <hip/hip_runtime.h>
#include <stdint.h>

typedef unsigned short u16;
typedef unsigned int u32;
typedef __bf16 bf16x8 __attribute__((ext_vector_type(8)));
typedef float f32x4 __attribute__((ext_vector_type(4)));
typedef unsigned short u16x8 __attribute__((ext_vector_type(8)));

#define D_MODEL 1024
#define SEQ 2048
#define NH 16
#define DK 64
#define NROWS 4096  // B*S

static __device__ __forceinline__ u16 f2bf(float f) {
  u32 u = __float_as_uint(f);
  u = (u + 0x7FFFu + ((u >> 16) & 1u)) >> 16;
  return (u16)u;
}
static __device__ __forceinline__ float bf2f(u16 h) {
  return __uint_as_float(((u32)h) << 16);
}
static __device__ __forceinline__ f32x4 mfma16(bf16x8 a, bf16x8 b, f32x4 c) {
  return __builtin_amdgcn_mfma_f32_16x16x32_bf16(a, b, c, 0, 0, 0);
}
static __device__ __forceinline__ void gload16(const void* g, void* l) {
  __builtin_amdgcn_global_load_lds(
      (const __attribute__((address_space(1))) void*)g,
      (__attribute__((address_space(3))) void*)l, 16, 0, 0);
}

// ---------------- fp32 -> bf16 cast of x and the 4 weight matrices ----------------
__global__ __launch_bounds__(256) void k_cast(
    const float* __restrict__ x, const float* __restrict__ wq,
    const float* __restrict__ wk, const float* __restrict__ wv,
    const float* __restrict__ wo, u16* __restrict__ xb, u16* __restrict__ wqb,
    u16* __restrict__ wkb, u16* __restrict__ wvb, u16* __restrict__ wob) {
  size_t e = ((size_t)blockIdx.x * 256 + threadIdx.x) * 8;
  const float* s;
  u16* d;
  size_t off;
  if (e < (size_t)NROWS * D_MODEL) {
    s = x; d = xb; off = e;
  } else {
    size_t r = e - (size_t)NROWS * D_MODEL;
    unsigned wi = (unsigned)(r >> 20);
    off = r & 1048575u;
    s = wi == 0 ? wq : wi == 1 ? wk : wi == 2 ? wv : wo;
    d = wi == 0 ? wqb : wi == 1 ? wkb : wi == 2 ? wvb : wob;
  }
  float4 a = *(const float4*)(s + off);
  float4 b = *(const float4*)(s + off + 4);
  u16x8 o;
  o[0] = f2bf(a.x); o[1] = f2bf(a.y); o[2] = f2bf(a.z); o[3] = f2bf(a.w);
  o[4] = f2bf(b.x); o[5] = f2bf(b.y); o[6] = f2bf(b.z); o[7] = f2bf(b.w);
  *(u16x8*)(d + off) = o;
}

// ---------------- RoPE tables (fp64 on device -> fp32 tables) ----------------
__global__ __launch_bounds__(256) void k_tab(float* __restrict__ ct, float* __restrict__ st) {
  int i = blockIdx.x * 256 + threadIdx.x;  // 2048*32
  int s = i >> 5, p = i & 31;
  double ang = (double)s * pow(10000.0, -(double)p / 32.0);
  ct[i] = (float)cos(ang);
  st[i] = (float)sin(ang);
}

// ---------------- bf16 B^T GEMM: C[M,N] = A[M,K] * B'[N,K]^T, K=1024 ----------------
// m97 structure: 128x128 tile, global_load_lds(16B) staging, linear LDS,
// 2 barriers/K-step, 4 waves of 64x64, 16x16x32 MFMA.
template <bool MULTI, bool OUTF32>
__global__ __launch_bounds__(256, 1) void k_gemm(
    const u16* __restrict__ A, const u16* __restrict__ B0,
    const u16* __restrict__ B1, const u16* __restrict__ B2,
    u16* __restrict__ Cb, float* __restrict__ Cf, int ldc) {
  constexpr int K = 1024;
  const int mb = blockIdx.x, nb = blockIdx.y;
  const int tid = threadIdx.x;
  const int lane = tid & 63, w = tid >> 6;
  const int lq = lane & 15, lg = lane >> 4;
  const int wm = w >> 1, wn = w & 1;
  __shared__ __align__(16) u16 As[128 * 32];
  __shared__ __align__(16) u16 Bs[128 * 32];

  const u16* Bp;
  if (MULTI) {
    int sel = nb >> 3;
    Bp = sel == 0 ? B0 : (sel == 1 ? B1 : B2);
  } else {
    Bp = B0;
  }
  int nloc = MULTI ? (nb & 7) * 128 : nb * 128;
  const char* Ab = (const char*)A + (size_t)mb * 128 * 2048;
  const char* Bb = (const char*)Bp + (size_t)nloc * 2048;

  const int srow = tid >> 2;       // 0..63
  const int scb = (tid & 3) * 16;  // 0,16,32,48 byte col

  f32x4 zero4 = {0.f, 0.f, 0.f, 0.f};
  f32x4 acc[4][4];
#pragma unroll
  for (int i = 0; i < 4; ++i)
#pragma unroll
    for (int j = 0; j < 4; ++j) acc[i][j] = zero4;

  for (int k0 = 0; k0 < K; k0 += 32) {
#pragma unroll
    for (int c = 0; c < 2; ++c) {
      int o = c * 4096 + tid * 16;  // linear LDS byte offset == lane order
      const char* ga = Ab + (size_t)(c * 64 + srow) * 2048 + k0 * 2 + scb;
      const char* gb = Bb + (size_t)(c * 64 + srow) * 2048 + k0 * 2 + scb;
      gload16(ga, (char*)As + o);
      gload16(gb, (char*)Bs + o);
    }
    __syncthreads();  // drains DMA (vmcnt) + aligns waves
    bf16x8 af[4], bfr[4];
#pragma unroll
    for (int i = 0; i < 4; ++i) {
      af[i] = *(const bf16x8*)((const char*)As + (wm * 64 + i * 16 + lq) * 64 + lg * 16);
      bfr[i] = *(const bf16x8*)((const char*)Bs + (wn * 64 + i * 16 + lq) * 64 + lg * 16);
    }
#pragma unroll
    for (int i = 0; i < 4; ++i)
#pragma unroll
      for (int j = 0; j < 4; ++j) acc[i][j] = mfma16(af[i], bfr[j], acc[i][j]);
    __syncthreads();  // all reads done before next-tile DMA overwrites
  }

#pragma unroll
  for (int i = 0; i < 4; ++i) {
#pragma unroll
    for (int r = 0; r < 4; ++r) {
      size_t rowg = (size_t)(mb * 128 + wm * 64 + i * 16 + lg * 4 + r);
#pragma unroll
      for (int j = 0; j < 4; ++j) {
        int colg = nb * 128 + wn * 64 + j * 16 + lq;
        if (OUTF32)
          Cf[rowg * ldc + colg] = acc[i][j][r];
        else
          Cb[rowg * ldc + colg] = f2bf(acc[i][j][r]);
      }
    }
  }
}

// ---------------- RoPE apply + reshape to head-major [BH][S][64] ----------------
__global__ __launch_bounds__(256) void k_rope(const u16* __restrict__ qkv,
                                              const float* __restrict__ ct,
                                              const float* __restrict__ st,
                                              u16* __restrict__ qh, u16* __restrict__ kh) {
  int gi = blockIdx.x * 256 + threadIdx.x;  // 524288
  int row = gi >> 7;
  int col = (gi & 127) << 3;
  int h = col >> 6, d0 = col & 63;
  int b = row >> 11, s = row & 2047;
  const int srcoff = blockIdx.y ? 1024 : 0;
  u16x8 v = *(const u16x8*)(qkv + (size_t)row * 3072 + srcoff + col);
  const float* cp = ct + s * 32 + (d0 >> 1);
  const float* sp = st + s * 32 + (d0 >> 1);
  u16x8 o;
#pragma unroll
  for (int i = 0; i < 4; ++i) {
    float ev = bf2f(v[2 * i]), od = bf2f(v[2 * i + 1]);
    float c = cp[i], sn = sp[i];
    o[2 * i] = f2bf(ev * c - od * sn);
    o[2 * i + 1] = f2bf(ev * sn + od * c);
  }
  u16* dst = blockIdx.y ? kh : qh;
  *(u16x8*)(dst + (((size_t)(b * 16 + h) * SEQ + s) << 6) + d0) = o;
}

// ---------------- V transpose: qkv V cols -> Vt [BH][64][S] ----------------
__global__ __launch_bounds__(256) void k_vtrans(const u16* __restrict__ qkv,
                                                u16* __restrict__ vt) {
  __shared__ __align__(16) u16 t[64][72];
  int sb = blockIdx.x, bh = blockIdx.y;
  int b = bh >> 4, h = bh & 15;
  int tid = threadIdx.x;
#pragma unroll
  for (int c = 0; c < 2; ++c) {
    int o = tid * 8 + c * 2048;
    int r = o >> 6, d = o & 63;
    u16x8 v = *(const u16x8*)(qkv + (size_t)(b * SEQ + sb * 64 + r) * 3072 + 2048 + h * 64 + d);
    *(u16x8*)&t[r][d] = v;
  }
  __syncthreads();
#pragma unroll
  for (int c = 0; c < 2; ++c) {
    int o = tid * 8 + c * 2048;
    int d = o >> 6, si = o & 63;
    u16x8 v;
#pragma unroll
    for (int j = 0; j < 8; ++j) v[j] = t[si + j][d];
    *(u16x8*)(vt + ((size_t)bh * 64 + d) * SEQ + sb * 64 + si) = v;
  }
}

// ---------------- one kv-tile of flash attention for one 16-row strip ----------------
static __device__ __forceinline__ void attn_tile(
    const u16* Kl, const u16* Vl, u16* Plw, int k0, int qrow, int lq, int lg,
    bf16x8 qf0, bf16x8 qf1, float& m_run, float& l_run, f32x4* accO) {
  f32x4 zero4 = {0.f, 0.f, 0.f, 0.f};
  const float SCL = 0.180336880f;  // 0.125 * log2(e): exp2 domain
  // QK^T, swapped: D[key][q]
  f32x4 sa[4];
  sa[0] = zero4; sa[1] = zero4; sa[2] = zero4; sa[3] = zero4;
  __builtin_amdgcn_s_setprio(1);
#pragma unroll
  for (int kt = 0; kt < 4; ++kt) {
    int krow = kt * 16 + lq;
    int base = krow * 128 + lg * 16;
    int swz = (krow & 7) << 4;
    bf16x8 kf0 = *(const bf16x8*)((const char*)Kl + (base ^ swz));
    bf16x8 kf1 = *(const bf16x8*)((const char*)Kl + ((base + 64) ^ swz));
    sa[kt] = mfma16(kf0, qf0, sa[kt]);
    sa[kt] = mfma16(kf1, qf1, sa[kt]);
  }
  __builtin_amdgcn_s_setprio(0);

  // masked online softmax (exp2 domain); lane owns q-row lq
  float p[16];
  float pm = -1e30f;
#pragma unroll
  for (int kt = 0; kt < 4; ++kt) {
#pragma unroll
    for (int r = 0; r < 4; ++r) {
      int key = k0 + kt * 16 + lg * 4 + r;
      float sv = sa[kt][r] * SCL;
      sv = (key <= qrow) ? sv : -1e30f;
      p[kt * 4 + r] = sv;
      pm = fmaxf(pm, sv);
    }
  }
  pm = fmaxf(pm, __shfl_xor(pm, 16));
  pm = fmaxf(pm, __shfl_xor(pm, 32));
  const bool resc = __any(pm > m_run + 8.0f);  // defer-max, wave-uniform
  float mnew = resc ? fmaxf(m_run, pm) : m_run;
  float rs = 0.f;
#pragma unroll
  for (int i = 0; i < 16; ++i) {
    p[i] = __builtin_amdgcn_exp2f(p[i] - mnew);
    rs += p[i];
  }
  rs += __shfl_xor(rs, 16);
  rs += __shfl_xor(rs, 32);
  if (resc) {
    float alpha = __builtin_amdgcn_exp2f(m_run - mnew);
    l_run = l_run * alpha + rs;
    m_run = mnew;
#pragma unroll
    for (int r = 0; r < 4; ++r) {
      float ar = __shfl(alpha, lg * 4 + r);
#pragma unroll
      for (int dt = 0; dt < 4; ++dt) accO[dt][r] *= ar;
    }
  } else {
    l_run += rs;
  }

  // P -> per-wave LDS (bf16 via v_cvt_pk, swizzled [q][k])
  {
    int swz = (lq & 7) << 4;
#pragma unroll
    for (int kt = 0; kt < 4; ++kt) {
      u32 w0, w1;
      asm("v_cvt_pk_bf16_f32 %0, %1, %2"
          : "=v"(w0) : "v"(p[kt * 4 + 0]), "v"(p[kt * 4 + 1]));
      asm("v_cvt_pk_bf16_f32 %0, %1, %2"
          : "=v"(w1) : "v"(p[kt * 4 + 2]), "v"(p[kt * 4 + 3]));
      int a0 = (lq * 128 + (kt * 16 + lg * 4) * 2) ^ swz;
      int a1 = (lq * 128 + (kt * 16 + lg * 4 + 2) * 2) ^ swz;
      *(u32*)((char*)Plw + a0) = w0;
      *(u32*)((char*)Plw + a1) = w1;
    }
  }
  // PV: O[q][d] += P[q][k] * V[k][d], V from transposed tile
  {
    int swz = (lq & 7) << 4;
    bf16x8 pa0 = *(const bf16x8*)((const char*)Plw + ((lq * 128 + lg * 16) ^ swz));
    bf16x8 pa1 = *(const bf16x8*)((const char*)Plw + ((lq * 128 + 64 + lg * 16) ^ swz));
    __builtin_amdgcn_s_setprio(1);
#pragma unroll
    for (int dt = 0; dt < 4; ++dt) {
      int vrow = dt * 16 + lq;
      int vb = vrow * 128 + lg * 16;
      int vs = (vrow & 7) << 4;
      bf16x8 v0 = *(const bf16x8*)((const char*)Vl + (vb ^ vs));
      bf16x8 v1 = *(const bf16x8*)((const char*)Vl + ((vb + 64) ^ vs));
      accO[dt] = mfma16(pa0, v0, accO[dt]);
      accO[dt] = mfma16(pa1, v1, accO[dt]);
    }
    __builtin_amdgcn_s_setprio(0);
  }
}

// ---------------- causal flash attention ----------------
// grid (8 paired qblocks, 32 bh); 512 threads = 8 waves.
// Block handles q-blocks qb1=x and qb2=15-x (128 rows each): per-wave work is
// 32+2*(w/4) kv-tiles for EVERY block -> perfect balance, grid = 256 = 1/CU.
// K/V staged once per tile via global_load_lds into LDS double buffer
// (linear dest + inverse-swizzled source, m201 stage_rc pattern);
// ONE barrier per tile; both strips share the staged tile (ILP within wave).
__global__ __launch_bounds__(512, 2) void k_attn(const u16* __restrict__ qh,
                                                 const u16* __restrict__ kh,
                                                 const u16* __restrict__ vt,
                                                 u16* __restrict__ ao) {
  const int qb1 = (int)blockIdx.x;       // 0..7 (light half)
  const int qb2 = 15 - qb1;              // 8..15 (heavy half)
  const int bh = blockIdx.y;
  const int tid = threadIdx.x;
  const int w = tid >> 6;  // 0..7
  const int lane = tid & 63;
  const int lq = lane & 15;
  const int lg = lane >> 4;

  __shared__ __align__(16) u16 Kd[2][64 * 64];
  __shared__ __align__(16) u16 Vd[2][64 * 64];
  __shared__ __align__(16) u16 Pl[8][16 * 64];

  const int qtop1 = qb1 * 128 + w * 16;
  const int qtop2 = qb2 * 128 + w * 16;
  const int qrow1 = qtop1 + lq;
  const int qrow2 = qtop2 + lq;

  const u16* qp1 = qh + ((size_t)bh * SEQ + qrow1) * DK + lg * 8;
  const u16* qp2 = qh + ((size_t)bh * SEQ + qrow2) * DK + lg * 8;
  bf16x8 qa0 = *(const bf16x8*)qp1;
  bf16x8 qa1 = *(const bf16x8*)(qp1 + 32);
  bf16x8 qb0 = *(const bf16x8*)qp2;
  bf16x8 qb1f = *(const bf16x8*)(qp2 + 32);

  f32x4 zero4 = {0.f, 0.f, 0.f, 0.f};
  f32x4 acc1[4], acc2[4];
#pragma unroll
  for (int dt = 0; dt < 4; ++dt) { acc1[dt] = zero4; acc2[dt] = zero4; }
  float m1 = -1e30f, l1 = 0.f, m2 = -1e30f, l2 = 0.f;

  const int NT = 2 * qb2 + 2;                // block-uniform tile count
  const int nt1 = 2 * qb1 + (w >> 2) + 1;    // strip participation bounds
  const int nt2 = 2 * qb2 + (w >> 2) + 1;

  // staging: linear LDS dest (tid*16), inverse-swizzled global source col
  const int srow = tid >> 3;       // 0..63
  const int scb = (tid & 7) * 16;  // byte col
  const int colb = scb ^ ((srow & 7) << 4);
  const char* kbase = (const char*)(kh + ((size_t)bh * SEQ + srow) * DK) + colb;
  const char* vbase = (const char*)(vt + ((size_t)bh * DK + srow) * SEQ) + colb;

  gload16(kbase, (char*)Kd[0] + tid * 16);
  gload16(vbase, (char*)Vd[0] + tid * 16);
  __syncthreads();  // drains DMA

  for (int t = 0; t < NT; ++t) {
    const int cur = t & 1;
    if (t + 1 < NT) {  // issue next-tile DMA early; lands during compute
      gload16(kbase + (size_t)(t + 1) * 8192, (char*)Kd[cur ^ 1] + tid * 16);
      gload16(vbase + (size_t)(t + 1) * 128, (char*)Vd[cur ^ 1] + tid * 16);
    }
    const int k0 = t * 64;
    if (t < nt1)
      attn_tile(Kd[cur], Vd[cur], Pl[w], k0, qrow1, lq, lg, qa0, qa1, m1, l1, acc1);
    if (t < nt2)
      attn_tile(Kd[cur], Vd[cur], Pl[w], k0, qrow2, lq, lg, qb0, qb1f, m2, l2, acc2);
    __syncthreads();  // one barrier per tile (drains next-tile DMA too)
  }

  const int b = bh >> 4, h = bh & 15;
#pragma unroll
  for (int r = 0; r < 4; ++r) {
    float lr = __shfl(l1, lg * 4 + r);
    float inv = 1.f / (lr + 1e-9f);
    int qq = qtop1 + lg * 4 + r;
    u16* orow = ao + ((size_t)b * SEQ + qq) * D_MODEL + h * DK;
#pragma unroll
    for (int dt = 0; dt < 4; ++dt) orow[dt * 16 + lq] = f2bf(acc1[dt][r] * inv);
  }
#pragma unroll
  for (int r = 0; r < 4; ++r) {
    float lr = __shfl(l2, lg * 4 + r);
    float inv = 1.f / (lr + 1e-9f);
    int qq = qtop2 + lg * 4 + r;
    u16* orow = ao + ((size_t)b * SEQ + qq) * D_MODEL + h * DK;
#pragma unroll
    for (int dt = 0; dt < 4; ++dt) orow[dt * 16 + lq] = f2bf(acc2[dt][r] * inv);
  }
}

extern "C" void kernel_launch(void* const* d_in, const int* in_sizes, int n_in,
                              void* d_out, int out_size, void* d_ws, size_t ws_size,
                              hipStream_t stream) {
  const float* x = (const float*)d_in[0];
  const float* wq = (const float*)d_in[1];
  const float* wk = (const float*)d_in[2];
  const float* wv = (const float*)d_in[3];
  const float* wo = (const float*)d_in[4];
  float* out = (float*)d_out;
  char* ws = (char*)d_ws;

  u16* xb   = (u16*)(ws + 0);             // 8 MB
  u16* wqb  = (u16*)(ws + 8388608);       // 2 MB
  u16* wkb  = (u16*)(ws + 10485760);
  u16* wvb  = (u16*)(ws + 12582912);
  u16* wob  = (u16*)(ws + 14680064);
  u16* qkv  = (u16*)(ws + 16777216);      // 24 MB [4096][3072]
  u16* qhb  = (u16*)(ws + 41943040);      // 8 MB [32][2048][64]
  u16* khb  = (u16*)(ws + 50331648);      // 8 MB
  u16* vtb  = (u16*)(ws + 58720256);      // 8 MB [32][64][2048]
  u16* aob  = (u16*)(ws + 67108864);      // 8 MB [4096][1024]
  float* ct = (float*)(ws + 75497472);    // 256 KB
  float* st = (float*)(ws + 75759616);    // 256 KB

  k_cast<<<4096, 256, 0, stream>>>(x, wq, wk, wv, wo, xb, wqb, wkb, wvb, wob);
  k_tab<<<256, 256, 0, stream>>>(ct, st);
  k_gemm<true, false><<<dim3(32, 24), 256, 0, stream>>>(xb, wqb, wkb, wvb, qkv, nullptr, 3072);
  k_rope<<<dim3(2048, 2), 256, 0, stream>>>(qkv, ct, st, qhb, khb);
  k_vtrans<<<dim3(32, 32), 256, 0, stream>>>(qkv, vtb);
  k_attn<<<dim3(8, 32), 512, 0, stream>>>(qhb, khb, vtb, aob);
  k_gemm<false, true><<<dim3(32, 8), 256, 0, stream>>>(aob, wob, nullptr, nullptr, nullptr, out, 1024);
}